// Round 16
// baseline (28.149 us; speedup 1.0000x reference)
//
#include <hip/hip_runtime.h>
#include <math.h>

#define NQ     9
#define NDIM   256
#define NHID   130
#define NST    512
#define NBATCH 64
#define MCAP   460

__device__ __forceinline__ float softplusf(float x) {
    return (x > 0.f) ? (x + log1pf(expf(-x))) : log1pf(expf(x));
}

// DPP-based XOR lane swaps (VALU pipe):
template<int CTRL>
__device__ __forceinline__ float dpp_f(float v) {
    int i = __float_as_int(v);
    return __int_as_float(__builtin_amdgcn_update_dpp(i, i, CTRL, 0xF, 0xF, false));
}
__device__ __forceinline__ float swzx16(float v) {   // lane ^ 16 (DS fallback)
    return __int_as_float(__builtin_amdgcn_ds_swizzle(__float_as_int(v), 0x401F));
}
__device__ __forceinline__ float bperm(int addr, float v) {   // lane ^ 32 (DS fallback)
    return __int_as_float(__builtin_amdgcn_ds_bpermute(addr, __float_as_int(v)));
}

typedef unsigned uint2v __attribute__((ext_vector_type(2)));

// lane^16 via v_permlane16_swap (VALU): with both inputs = x, result pair is
// {x with hi-16-rows pulled from lo, x with lo-16-rows pulled from hi}:
//   res[0][l] = x[l & ~16], res[1][l] = x[l | 16]  ->  x[l^16] = bit16 ? res0 : res1
__device__ __forceinline__ float lx16(float v, bool hi) {
#if __has_builtin(__builtin_amdgcn_permlane16_swap)
    uint2v r = __builtin_amdgcn_permlane16_swap(__float_as_uint(v), __float_as_uint(v), false, false);
    return __uint_as_float(hi ? r[0] : r[1]);
#else
    return swzx16(v);
#endif
}
__device__ __forceinline__ float lx32(float v, bool hi, int bpaddr) {
#if __has_builtin(__builtin_amdgcn_permlane32_swap)
    uint2v r = __builtin_amdgcn_permlane32_swap(__float_as_uint(v), __float_as_uint(v), false, false);
    return __uint_as_float(hi ? r[0] : r[1]);
#else
    return bperm(bpaddr, v);
#endif
}

// Chebyshev step on REAL vectors: NR = (2*xhat)*CR - NR   (all-VALU)
#define MV(NR, CR)                                                            \
  do {                                                                        \
    _Pragma("unroll")                                                         \
    for (int r = 0; r < 8; ++r) {                                             \
      const float a = CR[r];                                                  \
      float yr = dg2[r] * a;                                                  \
      yr = fmaf(in2[0], CR[r^1], yr);                                         \
      yr = fmaf(in2[1], CR[r^2], yr);                                         \
      yr = fmaf(in2[2], CR[r^4], yr);                                         \
      yr = fmaf(cx2[0], dpp_f<0xB1>(a), yr);                                  \
      yr = fmaf(cx2[1], dpp_f<0x4E>(a), yr);                                  \
      const float a7 = dpp_f<0x141>(a);                                       \
      yr = fmaf(cx2[2], dpp_f<0x1B>(a7), yr);                                 \
      yr = fmaf(cx2[3], dpp_f<0x140>(a7), yr);                                \
      yr = fmaf(cx2[4], lx16(a, h16), yr);                                    \
      yr = fmaf(cx2[5], lx32(a, h32, bpaddr), yr);                            \
      NR[r] = yr - NR[r];                                                     \
    }                                                                         \
  } while (0)

#define COEF(P, K)                                                            \
  do { const float ck = 2.0f * jlf[K];                                        \
    switch ((K) & 3) {                                                        \
      case 0: _Pragma("unroll") for (int r=0;r<8;++r) accr[r] += ck*P[r]; break; \
      case 1: _Pragma("unroll") for (int r=0;r<8;++r) acci[r] -= ck*P[r]; break; \
      case 2: _Pragma("unroll") for (int r=0;r<8;++r) accr[r] -= ck*P[r]; break; \
      case 3: _Pragma("unroll") for (int r=0;r<8;++r) acci[r] += ck*P[r]; break; \
    }                                                                         \
  } while (0)

// FUSED: one block per batch, 256 threads.
// Prologue (overlapped): waves 1-3 stage W1+x (coalesced float4) while wave 0
//   loads mask/adj, builds Wm, and computes the v-independent diagonal parts
//   (interaction Dsum, occupation mo).
// MLP: layer1 (130 threads, dual accumulators), layer2 (warp reductions).
// Evolution (wave 0 only, lockstep, barrier-free): gauge-transformed REAL
//   Chebyshev; cross-lane via DPP + permlane16/32_swap (all VALU).
__global__ __launch_bounds__(256) void fused_kernel(
    const float* __restrict__ x,    const float* __restrict__ mask,
    const float* __restrict__ adj,  const float* __restrict__ W1,
    const float* __restrict__ b1,   const float* __restrict__ W2,
    const float* __restrict__ b2,   float* __restrict__ out)
{
    const int b    = blockIdx.x;
    const int tid  = threadIdx.x;
    const int w    = tid >> 6;
    const int lane = tid & 63;

    __shared__ __align__(16) float w1s[NDIM * NHID];   // 133 KB; aliased later
    __shared__ float xs[NDIM];
    __shared__ float hs[NHID + 2];
    __shared__ float vs[4];
    __shared__ float ms[NQ];
    __shared__ float Wm[81];
    __shared__ double Ssh;

    float Dsum[8], mo[8];

    if (w != 0) {
        // ---- waves 1-3: stage W1 + x (coalesced float4) ----
        const int t0 = tid - 64;                 // 0..191
        const float4* W14 = (const float4*)W1;
        float4* d4 = (float4*)w1s;
        for (int i = t0; i < (NDIM*NHID)/4; i += 192) d4[i] = W14[i];
        if (t0 < NDIM/4) ((float4*)xs)[t0] = ((const float4*)(x + b*NDIM))[t0];
    } else {
        // ---- wave 0: mask, Wm, v-independent diagonal parts ----
        if (lane < NQ) ms[lane] = mask[b*NQ + lane];
        for (int e = lane; e < 81; e += 64) {
            int i = e / 9, j = e % 9;
            Wm[e] = (866.0f/729.0f) * adj[e] * ms[i] * ms[j];   // in-wave LDS order
        }
        #pragma unroll
        for (int r = 0; r < 8; ++r) {
            const int s = (lane << 3) | r;
            float d = 0.f, m = 0.f;
            #pragma unroll
            for (int i = 0; i < NQ; ++i) {
                float oi = ((s >> (8 - i)) & 1) ? 0.f : 1.f;
                m = fmaf(ms[i], oi, m);
                float row = 0.f;
                #pragma unroll
                for (int j = 0; j < NQ; ++j) {
                    float oj = ((s >> (8 - j)) & 1) ? 0.f : 1.f;
                    row = fmaf(Wm[i*9 + j], oj, row);
                }
                d = fmaf(oi, row, d);
            }
            Dsum[r] = d; mo[r] = m;
        }
    }
    __syncthreads();

    // ---- layer 1: hidden = relu(x @ W1 + b1), dual accumulators ----
    if (tid < NHID) {
        float a0 = b1[tid], a1 = 0.f;
        #pragma unroll 8
        for (int i = 0; i < NDIM; i += 2) {
            a0 = fmaf(xs[i],     w1s[i*NHID + tid],       a0);
            a1 = fmaf(xs[i + 1], w1s[(i + 1)*NHID + tid], a1);
        }
        hs[tid] = fmaxf(a0 + a1, 0.f);
    }
    __syncthreads();

    // ---- layer 2: warp w computes v[w] via wave reduction ----
    {
        float p = hs[lane]      * W2[lane*4 + w]
                + hs[lane + 64] * W2[(lane + 64)*4 + w];
        if (lane < 2) p += hs[128 + lane] * W2[(128 + lane)*4 + w];
        #pragma unroll
        for (int off = 32; off; off >>= 1) p += __shfl_down(p, off);
        if (lane == 0) vs[w] = p + b2[w];
    }
    __syncthreads();

    if (w != 0) return;   // wave 0 evolves, lockstep, barrier-free

    // Bessel tables alias the dead W1 staging region.
    double* fd  = (double*)w1s;
    float*  jlf = w1s + 2*(MCAP + 8);

    const float omega = softplusf(vs[0]);
    const float delta = vs[1];
    const float phi   = vs[2];
    const float t     = softplusf(vs[3]);
    const float halfw = 0.5f * omega;

    float Dd[8];
    #pragma unroll
    for (int r = 0; r < 8; ++r) Dd[r] = Dsum[r] - delta * mo[r];

    // ---- spectral interval ----
    float mx = Dd[0], mn = Dd[0];
    #pragma unroll
    for (int r = 1; r < 8; ++r) { mx = fmaxf(mx, Dd[r]); mn = fminf(mn, Dd[r]); }
    #pragma unroll
    for (int off = 1; off < 64; off <<= 1) {
        mx = fmaxf(mx, __shfl_xor(mx, off));
        mn = fminf(mn, __shfl_xor(mn, off));
    }
    float sm = 0.f;
    #pragma unroll
    for (int j = 0; j < NQ; ++j) sm += ms[j];
    const float c0   = 0.5f * (mx + mn);
    const float rho  = (0.5f * (mx - mn) + halfw * sm) * 1.003f;
    const float rhoE = fmaxf(rho, 1e-20f);
    const float zc   = t * rho;

    int M;
    const bool tiny = (zc < 0.5f);
    if (tiny) M = 8;
    else {
        M = (int)ceilf(zc + 3.5f * cbrtf(zc + 4.f) + 4.f);
        if (M > MCAP) M = MCAP;
    }

    // ---- Bessel table J_0..J_M (lockstep, no barriers) ----
    if (tiny) {
        if (lane <= 8) {
            const float zh = 0.5f * zc;
            const float q  = zh * zh;
            float fact = 1.f;
            for (int i = 2; i <= lane; ++i) fact *= (float)i;
            const float pw = (lane == 0) ? 1.f : powf(zh, (float)lane);
            jlf[lane] = (pw / fact) *
                (1.f - q/(float)(lane+1) + 0.5f*q*q/(float)((lane+1)*(lane+2)));
        }
    } else {
        if (lane == 0) {
            const double zz  = (double)zc;
            const double inv = 1.0 / zz;
            const int   M2   = M + 20 + M/10;
            double fkp1 = 0.0, fk = 1e-30;
            for (int k = M2; k >= 1; --k) {
                double fkm1 = 2.0 * (double)k * inv * fk - fkp1;
                fkp1 = fk; fk = fkm1;
                const int idx = k - 1;
                if (idx <= M) fd[idx] = fk;
            }
            double S = fd[0];
            for (int idx = 2; idx <= M; idx += 2) S += 2.0 * fd[idx];
            Ssh = S;
        }
        for (int k = lane; k <= M; k += 64) jlf[k] = (float)(fd[k] / Ssh);
    }

    // ---- folded REAL coefficients of 2*xhat ----
    const float two_rho = 2.0f / rhoE;
    float dg2[8];
    #pragma unroll
    for (int r = 0; r < 8; ++r) dg2[r] = (Dd[r] - c0) * two_rho;
    float cx2[6];
    #pragma unroll
    for (int q = 0; q < 6; ++q) cx2[q] = ms[5 - q] * halfw * two_rho;
    float in2[3];
    #pragma unroll
    for (int p = 0; p < 3; ++p) in2[p] = ms[8 - p] * halfw * two_rho;
    const int  bpaddr = (lane ^ 32) << 2;
    const bool h16    = (lane & 16) != 0;
    const bool h32    = (lane & 32) != 0;

    // ---- Chebyshev recurrence (REAL vectors) ----
    float p0[8], p1[8], accr[8], acci[8];
    #pragma unroll
    for (int r = 0; r < 8; ++r) { p0[r] = 0.f; p1[r] = 0.f; acci[r] = 0.f; }
    p0[0] = (lane == 0) ? 1.f : 0.f;

    const float J0 = jlf[0];
    #pragma unroll
    for (int r = 0; r < 8; ++r) accr[r] = J0 * p0[r];

    MV(p1, p0);
    #pragma unroll
    for (int r = 0; r < 8; ++r) p1[r] *= 0.5f;
    { const float c1 = 2.0f * jlf[1];
      #pragma unroll
      for (int r = 0; r < 8; ++r) acci[r] -= c1 * p1[r]; }

    int k = 2;
    while (k <= M) {
        MV(p0, p1);
        COEF(p0, k);
        ++k;
        if (k > M) break;
        MV(p1, p0);
        COEF(p1, k);
        ++k;
    }

    // ---- undo gauge + shift; packed float4 stores ----
    const float base = t * c0;
    const float pcl  = (float)__popc(lane);
    float o[8];
    #pragma unroll
    for (int r = 0; r < 8; ++r) {
        const float beta = base + phi * (pcl + (float)__popc(r));
        float sb, cbta;
        __sincosf(beta, &sb, &cbta);
        o[r] = accr[r]*cbta + acci[r]*sb;
    }
    float4* o4 = (float4*)(out + b*NST + (lane << 3));
    o4[0] = make_float4(o[0], o[1], o[2], o[3]);
    o4[1] = make_float4(o[4], o[5], o[6], o[7]);
}

extern "C" void kernel_launch(void* const* d_in, const int* in_sizes, int n_in,
                              void* d_out, int out_size, void* d_ws, size_t ws_size,
                              hipStream_t stream) {
    // Size-keyed input routing (pairwise-distinct element counts):
    //   x:16384  mask:576  adj:81  W1:33280  b1:130  W2:520  b2:4
    const float *x = nullptr, *msk = nullptr, *adj = nullptr,
                *W1 = nullptr, *b1 = nullptr, *W2 = nullptr, *b2 = nullptr;
    for (int i = 0; i < n_in; ++i) {
        const float* p = (const float*)d_in[i];
        switch (in_sizes[i]) {
            case 16384: x   = p; break;
            case 576:   msk = p; break;
            case 81:    adj = p; break;
            case 33280: W1  = p; break;
            case 130:   b1  = p; break;
            case 520:   W2  = p; break;
            case 4:     b2  = p; break;
            default: break;
        }
    }
    fused_kernel<<<NBATCH, 256, 0, stream>>>(x, msk, adj, W1, b1, W2, b2,
                                             (float*)d_out);
}

// Round 17
// 25.298 us; speedup vs baseline: 1.1127x; 1.1127x over previous
//
#include <hip/hip_runtime.h>
#include <math.h>

#define NQ     9
#define NDIM   256
#define NHID   130
#define NST    512
#define NBATCH 64
#define MCAP   460

__device__ __forceinline__ float softplusf(float x) {
    return (x > 0.f) ? (x + log1pf(expf(-x))) : log1pf(expf(x));
}

// DPP-based XOR lane swaps (VALU pipe):
template<int CTRL>
__device__ __forceinline__ float dpp_f(float v) {
    int i = __float_as_int(v);
    return __int_as_float(__builtin_amdgcn_update_dpp(i, i, CTRL, 0xF, 0xF, false));
}
__device__ __forceinline__ float swzx16(float v) {   // lane ^ 16 (DS fallback)
    return __int_as_float(__builtin_amdgcn_ds_swizzle(__float_as_int(v), 0x401F));
}
__device__ __forceinline__ float bperm(int addr, float v) {   // lane ^ 32 (DS fallback)
    return __int_as_float(__builtin_amdgcn_ds_bpermute(addr, __float_as_int(v)));
}

typedef unsigned uint2v __attribute__((ext_vector_type(2)));

__device__ __forceinline__ float lx16(float v, bool hi) {
#if __has_builtin(__builtin_amdgcn_permlane16_swap)
    uint2v r = __builtin_amdgcn_permlane16_swap(__float_as_uint(v), __float_as_uint(v), false, false);
    return __uint_as_float(hi ? r[0] : r[1]);
#else
    return swzx16(v);
#endif
}
__device__ __forceinline__ float lx32(float v, bool hi, int bpaddr) {
#if __has_builtin(__builtin_amdgcn_permlane32_swap)
    uint2v r = __builtin_amdgcn_permlane32_swap(__float_as_uint(v), __float_as_uint(v), false, false);
    return __uint_as_float(hi ? r[0] : r[1]);
#else
    return bperm(bpaddr, v);
#endif
}

// Chebyshev step on REAL vectors: NR = (2*xhat)*CR - NR   (all-VALU)
#define MV(NR, CR)                                                            \
  do {                                                                        \
    _Pragma("unroll")                                                         \
    for (int r = 0; r < 8; ++r) {                                             \
      const float a = CR[r];                                                  \
      float yr = dg2[r] * a;                                                  \
      yr = fmaf(in2[0], CR[r^1], yr);                                         \
      yr = fmaf(in2[1], CR[r^2], yr);                                         \
      yr = fmaf(in2[2], CR[r^4], yr);                                         \
      yr = fmaf(cx2[0], dpp_f<0xB1>(a), yr);                                  \
      yr = fmaf(cx2[1], dpp_f<0x4E>(a), yr);                                  \
      const float a7 = dpp_f<0x141>(a);                                       \
      yr = fmaf(cx2[2], dpp_f<0x1B>(a7), yr);                                 \
      yr = fmaf(cx2[3], dpp_f<0x140>(a7), yr);                                \
      yr = fmaf(cx2[4], lx16(a, h16), yr);                                    \
      yr = fmaf(cx2[5], lx32(a, h32, bpaddr), yr);                            \
      NR[r] = yr - NR[r];                                                     \
    }                                                                         \
  } while (0)

#define COEF(P, K)                                                            \
  do { const float ck = 2.0f * jlf[K];                                        \
    switch ((K) & 3) {                                                        \
      case 0: _Pragma("unroll") for (int r=0;r<8;++r) accr[r] += ck*P[r]; break; \
      case 1: _Pragma("unroll") for (int r=0;r<8;++r) acci[r] -= ck*P[r]; break; \
      case 2: _Pragma("unroll") for (int r=0;r<8;++r) accr[r] -= ck*P[r]; break; \
      case 3: _Pragma("unroll") for (int r=0;r<8;++r) acci[r] += ck*P[r]; break; \
    }                                                                         \
  } while (0)

// FUSED, code-size-minimized. One block per batch, 256 threads.
// Stage (all 256): W1 -> LDS float4, x, mask, adj. MLP: layer1 (130 thr),
// layer2 (4 warp reductions). Evolution (wave 0 only, lockstep): diagonal via
// lane/reg occupancy factorization (rolled 6x6+6x3 loops + compile-time
// r-terms), then REAL Chebyshev with DPP/permlane cross-lane.
__global__ __launch_bounds__(256) void fused_kernel(
    const float* __restrict__ x,    const float* __restrict__ mask,
    const float* __restrict__ adj,  const float* __restrict__ W1,
    const float* __restrict__ b1,   const float* __restrict__ W2,
    const float* __restrict__ b2,   float* __restrict__ out)
{
    const int b    = blockIdx.x;
    const int tid  = threadIdx.x;
    const int w    = tid >> 6;
    const int lane = tid & 63;

    __shared__ __align__(16) float w1s[NDIM * NHID];   // 133 KB; aliased later
    __shared__ float xs[NDIM];
    __shared__ float hs[NHID + 2];
    __shared__ float vs[4];
    __shared__ float ms[NQ];
    __shared__ float adjs[81];
    __shared__ float Wm[81];
    __shared__ double Ssh;

    // ---- stage: W1 (all threads, float4), x, mask, adj ----
    {
        const float4* W14 = (const float4*)W1;
        float4* d4 = (float4*)w1s;
        #pragma unroll 4
        for (int i = tid; i < (NDIM*NHID)/4; i += 256) d4[i] = W14[i];
        if (tid < NDIM/4) ((float4*)xs)[tid] = ((const float4*)(x + b*NDIM))[tid];
        if (tid >= 64 && tid < 64 + NQ) ms[tid - 64] = mask[b*NQ + (tid - 64)];
        if (tid >= 128 && tid < 128 + 81) adjs[tid - 128] = adj[tid - 128];
    }
    __syncthreads();

    // ---- layer 1: hidden = relu(x @ W1 + b1), dual accumulators ----
    if (tid < NHID) {
        float a0 = b1[tid], a1 = 0.f;
        #pragma unroll 8
        for (int i = 0; i < NDIM; i += 2) {
            a0 = fmaf(xs[i],     w1s[i*NHID + tid],       a0);
            a1 = fmaf(xs[i + 1], w1s[(i + 1)*NHID + tid], a1);
        }
        hs[tid] = fmaxf(a0 + a1, 0.f);
    }
    __syncthreads();

    // ---- layer 2: warp w computes v[w] via wave reduction ----
    {
        float p = hs[lane]      * W2[lane*4 + w]
                + hs[lane + 64] * W2[(lane + 64)*4 + w];
        if (lane < 2) p += hs[128 + lane] * W2[(128 + lane)*4 + w];
        #pragma unroll
        for (int off = 32; off; off >>= 1) p += __shfl_down(p, off);
        if (lane == 0) vs[w] = p + b2[w];
    }
    __syncthreads();

    if (w != 0) return;   // wave 0 evolves, lockstep, barrier-free

    // Bessel tables alias the dead W1 staging region.
    double* fd  = (double*)w1s;
    float*  jlf = w1s + 2*(MCAP + 8);

    // ---- weighted adjacency (rolled; in-wave LDS order) ----
    for (int e = lane; e < 81; e += 64) {
        int i = e / 9, j = e % 9;
        Wm[e] = (866.0f/729.0f) * adjs[e] * ms[i] * ms[j];
    }

    const float omega = softplusf(vs[0]);
    const float delta = vs[1];
    const float phi   = vs[2];
    const float t     = softplusf(vs[3]);
    const float halfw = 0.5f * omega;

    // ---- diagonal via occupancy factorization ----
    // s = lane<<3 | r; qubits 0..5 -> lane bits 5..0, qubits 6..8 -> r bits 2..0.
    float oL[6];
    #pragma unroll
    for (int i = 0; i < 6; ++i) oL[i] = ((lane >> (5 - i)) & 1) ? 0.f : 1.f;
    float t1 = 0.f, moL = 0.f;
    for (int i = 0; i < 6; ++i) {              // rolled (code-size)
        moL = fmaf(ms[i], oL[i], moL);
        float row = 0.f;
        for (int j = 0; j < 6; ++j) row = fmaf(Wm[i*9 + j], oL[j], row);
        t1 = fmaf(oL[i], row, t1);
    }
    float g[3];
    for (int p = 0; p < 3; ++p) {
        float gp = 0.f;
        for (int i = 0; i < 6; ++i) gp = fmaf(Wm[i*9 + 6 + p], oL[i], gp);
        g[p] = gp;
    }
    const float w67 = Wm[6*9 + 7], w68 = Wm[6*9 + 8], w78 = Wm[7*9 + 8];
    float Dd[8];
    #pragma unroll
    for (int r = 0; r < 8; ++r) {
        const float o0 = (r & 4) ? 0.f : 1.f;   // qubit 6
        const float o1 = (r & 2) ? 0.f : 1.f;   // qubit 7
        const float o2 = (r & 1) ? 0.f : 1.f;   // qubit 8
        const float cross = g[0]*o0 + g[1]*o1 + g[2]*o2;
        const float rr    = w67*o0*o1 + w68*o0*o2 + w78*o1*o2;
        const float mo_r  = moL + ms[6]*o0 + ms[7]*o1 + ms[8]*o2;
        Dd[r] = t1 + 2.f*(cross + rr) - delta*mo_r;
    }

    // ---- spectral interval ----
    float mx = Dd[0], mn = Dd[0];
    #pragma unroll
    for (int r = 1; r < 8; ++r) { mx = fmaxf(mx, Dd[r]); mn = fminf(mn, Dd[r]); }
    #pragma unroll
    for (int off = 1; off < 64; off <<= 1) {
        mx = fmaxf(mx, __shfl_xor(mx, off));
        mn = fminf(mn, __shfl_xor(mn, off));
    }
    float sm = 0.f;
    for (int j = 0; j < NQ; ++j) sm += ms[j];
    const float c0   = 0.5f * (mx + mn);
    const float rho  = (0.5f * (mx - mn) + halfw * sm) * 1.003f;
    const float rhoE = fmaxf(rho, 1e-20f);
    const float zc   = t * rho;

    int M;
    const bool tiny = (zc < 0.5f);
    if (tiny) M = 8;
    else {
        M = (int)ceilf(zc + 3.5f * cbrtf(zc + 4.f) + 4.f);
        if (M > MCAP) M = MCAP;
    }

    // ---- Bessel table J_0..J_M (lockstep, no barriers) ----
    if (tiny) {
        if (lane <= 8) {
            const float zh = 0.5f * zc;
            const float q  = zh * zh;
            float fact = 1.f;
            for (int i = 2; i <= lane; ++i) fact *= (float)i;
            const float pw = (lane == 0) ? 1.f : powf(zh, (float)lane);
            jlf[lane] = (pw / fact) *
                (1.f - q/(float)(lane+1) + 0.5f*q*q/(float)((lane+1)*(lane+2)));
        }
    } else {
        if (lane == 0) {
            const double zz  = (double)zc;
            const double inv = 1.0 / zz;
            const int   M2   = M + 20 + M/10;
            double fkp1 = 0.0, fk = 1e-30;
            for (int k = M2; k >= 1; --k) {
                double fkm1 = 2.0 * (double)k * inv * fk - fkp1;
                fkp1 = fk; fk = fkm1;
                const int idx = k - 1;
                if (idx <= M) fd[idx] = fk;
            }
            double S = fd[0];
            for (int idx = 2; idx <= M; idx += 2) S += 2.0 * fd[idx];
            Ssh = S;
        }
        for (int k = lane; k <= M; k += 64) jlf[k] = (float)(fd[k] / Ssh);
    }

    // ---- folded REAL coefficients of 2*xhat ----
    const float two_rho = 2.0f / rhoE;
    float dg2[8];
    #pragma unroll
    for (int r = 0; r < 8; ++r) dg2[r] = (Dd[r] - c0) * two_rho;
    float cx2[6];
    #pragma unroll
    for (int q = 0; q < 6; ++q) cx2[q] = ms[5 - q] * halfw * two_rho;
    float in2[3];
    #pragma unroll
    for (int p = 0; p < 3; ++p) in2[p] = ms[8 - p] * halfw * two_rho;
    const int  bpaddr = (lane ^ 32) << 2;
    const bool h16    = (lane & 16) != 0;
    const bool h32    = (lane & 32) != 0;

    // ---- Chebyshev recurrence (REAL vectors) ----
    float p0[8], p1[8], accr[8], acci[8];
    #pragma unroll
    for (int r = 0; r < 8; ++r) { p0[r] = 0.f; p1[r] = 0.f; acci[r] = 0.f; }
    p0[0] = (lane == 0) ? 1.f : 0.f;

    const float J0 = jlf[0];
    #pragma unroll
    for (int r = 0; r < 8; ++r) accr[r] = J0 * p0[r];

    MV(p1, p0);
    #pragma unroll
    for (int r = 0; r < 8; ++r) p1[r] *= 0.5f;
    { const float c1 = 2.0f * jlf[1];
      #pragma unroll
      for (int r = 0; r < 8; ++r) acci[r] -= c1 * p1[r]; }

    int k = 2;
    while (k <= M) {
        MV(p0, p1);
        COEF(p0, k);
        ++k;
        if (k > M) break;
        MV(p1, p0);
        COEF(p1, k);
        ++k;
    }

    // ---- undo gauge + shift; packed float4 stores ----
    const float base = t * c0;
    const float pcl  = (float)__popc(lane);
    float o[8];
    #pragma unroll
    for (int r = 0; r < 8; ++r) {
        const float beta = base + phi * (pcl + (float)__popc(r));
        float sb, cbta;
        __sincosf(beta, &sb, &cbta);
        o[r] = accr[r]*cbta + acci[r]*sb;
    }
    float4* o4 = (float4*)(out + b*NST + (lane << 3));
    o4[0] = make_float4(o[0], o[1], o[2], o[3]);
    o4[1] = make_float4(o[4], o[5], o[6], o[7]);
}

extern "C" void kernel_launch(void* const* d_in, const int* in_sizes, int n_in,
                              void* d_out, int out_size, void* d_ws, size_t ws_size,
                              hipStream_t stream) {
    // Size-keyed input routing (pairwise-distinct element counts):
    //   x:16384  mask:576  adj:81  W1:33280  b1:130  W2:520  b2:4
    const float *x = nullptr, *msk = nullptr, *adj = nullptr,
                *W1 = nullptr, *b1 = nullptr, *W2 = nullptr, *b2 = nullptr;
    for (int i = 0; i < n_in; ++i) {
        const float* p = (const float*)d_in[i];
        switch (in_sizes[i]) {
            case 16384: x   = p; break;
            case 576:   msk = p; break;
            case 81:    adj = p; break;
            case 33280: W1  = p; break;
            case 130:   b1  = p; break;
            case 520:   W2  = p; break;
            case 4:     b2  = p; break;
            default: break;
        }
    }
    fused_kernel<<<NBATCH, 256, 0, stream>>>(x, msk, adj, W1, b1, W2, b2,
                                             (float*)d_out);
}